// Round 9
// baseline (384.683 us; speedup 1.0000x reference)
//
#include <hip/hip_runtime.h>
#include <cstdint>
#include <cstddef>

#define B_ROWS 16384
#define DIMSZ  1024
#define NH     8
#define HD     128
#define KDIM   1024

typedef __attribute__((ext_vector_type(8))) __bf16 bf16x8;
typedef __attribute__((ext_vector_type(4))) float f32x4;
typedef __attribute__((ext_vector_type(8))) unsigned short ushort8v;
typedef __attribute__((ext_vector_type(4))) unsigned short ushort4v;

__device__ __forceinline__ unsigned short f2bf(float f) {
  union { float f; unsigned int u; } x; x.f = f;
  unsigned int r = x.u + 0x7FFFu + ((x.u >> 16) & 1u);   // RNE
  return (unsigned short)(r >> 16);
}
__device__ __forceinline__ float bf2f(unsigned short h) {
  union { unsigned int u; float f; } x; x.u = ((unsigned int)h) << 16;
  return x.f;
}

__device__ __forceinline__ void gload_lds16(const void* g, void* l) {
  __builtin_amdgcn_global_load_lds(
      (__attribute__((address_space(1))) void*)(uintptr_t)g,
      (__attribute__((address_space(3))) void*)(uintptr_t)l, 16, 0, 0);
}

// ---------------- all 4 weight transposes, one launch ------------------------
__global__ __launch_bounds__(256) void transpose_cvt4_k(
    const float* __restrict__ W0, const float* __restrict__ W1,
    const float* __restrict__ W2, const float* __restrict__ W3,
    unsigned short* __restrict__ T0, unsigned short* __restrict__ T1,
    unsigned short* __restrict__ T2, unsigned short* __restrict__ T3) {
  const float* W; unsigned short* T;
  switch (blockIdx.z) {
    case 0: W = W0; T = T0; break;
    case 1: W = W1; T = T1; break;
    case 2: W = W2; T = T2; break;
    default: W = W3; T = T3; break;
  }
  __shared__ float tile[32][33];
  int bx = blockIdx.x * 32, by = blockIdx.y * 32;
  int tx = threadIdx.x & 31, ty = threadIdx.x >> 5;
  #pragma unroll
  for (int j = ty; j < 32; j += 8)
    tile[j][tx] = W[(size_t)(by + j) * DIMSZ + bx + tx];
  __syncthreads();
  #pragma unroll
  for (int j = ty; j < 32; j += 8)
    T[(size_t)(bx + j) * DIMSZ + by + tx] = f2bf(tile[tx][j]);
}

// ---------------- bf16 MFMA GEMM, 128x128 tile ------------------------------
// C[M,NCOLS] = A[M,K] @ Bt[NCOLS,K]^T + bias.
// BM=BN=128, BK=64, 4 waves (2x2), per-wave 64x64, acc[4][4].
// Single 32 KB LDS buffer, 2 __syncthreads per K-tile; staging issued after
// the read-done barrier, BEFORE the 32-MFMA cluster; 3 blocks/CU cross-block
// overlap covers the barrier drains.  0-conflict XOR swizzle c' = c ^ (row&7)
// on 16B chunks.  T1 XCD swizzle.  Split epilogue for fused KV.  LDS-staged
// coalesced C stores.
// FP32A=1 (fused cvt): A fp32 in HBM, reg-staged.  STAGING ORDER IS CRITICAL
//   (R8 lesson): stageB first (gload_lds, no deps) -> writeA (waits only
//   vmcnt(4), its gA loads are ~1 iteration old) -> loadA(t+2) (after writeA:
//   register WAR on the single gA set).  R8's writeA-first order forced
//   vmcnt(0) full drains and ran 2.9x slower.
// FP32A=0: A bf16 via gload_lds (O GEMM).
// NOTE: __launch_bounds__ MUST stay (256,3): (256,4) caps VGPR at 64 ->
// accumulator spills -> 455MB scratch traffic, 2.4x slower (R6 regression).
template <int NCOLS, int OUT_BF16, int FP32A>
__global__ __launch_bounds__(256, 3) void gemm9_k(
    const void* __restrict__ Aq,
    const unsigned short* __restrict__ Bt,
    const float* __restrict__ bias0, const float* __restrict__ bias1,
    void* __restrict__ out0, void* __restrict__ out1) {
  constexpr int NBC = NCOLS / 128;
  constexpr int NWG = (B_ROWS / 128) * NBC;
  constexpr int NKT = KDIM / 64;   // 16

  __shared__ __align__(16) char smem[32768];   // A tile | B tile; C tile in epilogue
  char* Asm = smem;
  char* Bsm = smem + 16384;

  const int tid = threadIdx.x;
  const int wid = tid >> 6, lane = tid & 63;
  const int lr = lane & 15, kg = lane >> 4;
  const int wr = wid >> 1, wc = wid & 1;
  const int swz = lr & 7;

  // T1: XCD-aware block swizzle (NWG % 8 == 0 for all instantiations)
  const int x = ((int)blockIdx.x % 8) * (NWG / 8) + (int)blockIdx.x / 8;
  const int bcol = (x % NBC) * 128;
  const int brow = (x / NBC) * 128;

  const char* Bb = (const char*)(Bt + (size_t)bcol * KDIM);

  // ---- B (and bf16-A) staging: linear LDS dest, inverse-swizzled source ----
  int soff[4];
  #pragma unroll
  for (int j = 0; j < 4; ++j) {
    int D = j * 4096 + tid * 16;
    int row = D >> 7, c = (D >> 4) & 7;
    soff[j] = row * 2048 + ((c ^ (row & 7)) << 4);
  }
  auto stageB = [&](int t) {
    #pragma unroll
    for (int j = 0; j < 4; ++j)
      gload_lds16(Bb + (size_t)soff[j] + t * 128, Bsm + j * 4096 + tid * 16);
  };

  // ---- A: fp32 reg-staging path ----
  const float* Af = (const float*)Aq + (size_t)brow * KDIM;
  const int agbase = (tid >> 4) * KDIM + (tid & 15) * 4;      // floats
  const int albase = (tid >> 4) * 128 +
                     (((((tid & 15) >> 1) ^ ((tid >> 4) & 7))) << 4) +
                     (tid & 1) * 8;
  f32x4 gA[8];
  auto loadA = [&](int t) {
    #pragma unroll
    for (int j = 0; j < 8; ++j)
      gA[j] = *(const f32x4*)(Af + (size_t)j * 16 * KDIM + agbase + t * 64);
  };
  auto writeA = [&]() {
    #pragma unroll
    for (int j = 0; j < 8; ++j) {
      ushort4v h;
      h[0] = f2bf(gA[j][0]); h[1] = f2bf(gA[j][1]);
      h[2] = f2bf(gA[j][2]); h[3] = f2bf(gA[j][3]);
      *(ushort4v*)(Asm + j * 2048 + albase) = h;
    }
  };
  // ---- A: bf16 gload_lds path ----
  const char* Ab = (const char*)Aq + (size_t)brow * KDIM * 2;
  auto stageA16 = [&](int t) {
    #pragma unroll
    for (int j = 0; j < 4; ++j)
      gload_lds16(Ab + (size_t)soff[j] + t * 128, Asm + j * 4096 + tid * 16);
  };

  f32x4 acc[4][4] = {};

  // ---- prologue ----
  if constexpr (FP32A) {
    loadA(0);
    stageB(0);
    writeA();          // waits gA(0) only: vmcnt(4), B stays in flight
    loadA(1);
  } else {
    stageA16(0);
    stageB(0);
  }

  #pragma unroll 1
  for (int t = 0; t < NKT; ++t) {
    __syncthreads();   // stage(t) complete (vm + lgkm drained by barrier)

    bf16x8 af[4][2], bfr[4][2];
    #pragma unroll
    for (int m = 0; m < 4; ++m) {
      int row = wr * 64 + m * 16 + lr;
      #pragma unroll
      for (int kk = 0; kk < 2; ++kk)
        af[m][kk] = *(const bf16x8*)(Asm + row * 128 + (((kk * 4 + kg) ^ swz) << 4));
    }
    #pragma unroll
    for (int n = 0; n < 4; ++n) {
      int row = wc * 64 + n * 16 + lr;
      #pragma unroll
      for (int kk = 0; kk < 2; ++kk)
        bfr[n][kk] = *(const bf16x8*)(Bsm + row * 128 + (((kk * 4 + kg) ^ swz) << 4));
    }
    __syncthreads();   // all waves' reads done -> buffers free

    if (t + 1 < NKT) {
      if constexpr (FP32A) {
        stageB(t + 1);                  // independent: issue FIRST (R8 fix)
        writeA();                       // gA(t+1) -> LDS; waits vmcnt(4)
        if (t + 2 < NKT) loadA(t + 2);  // after writeA (reg WAR on gA)
      } else {
        stageA16(t + 1);
        stageB(t + 1);
      }
    }

    __builtin_amdgcn_s_setprio(1);
    #pragma unroll
    for (int m = 0; m < 4; ++m)
      #pragma unroll
      for (int n = 0; n < 4; ++n) {
        acc[m][n] = __builtin_amdgcn_mfma_f32_16x16x32_bf16(af[m][0], bfr[n][0], acc[m][n], 0, 0, 0);
        acc[m][n] = __builtin_amdgcn_mfma_f32_16x16x32_bf16(af[m][1], bfr[n][1], acc[m][n], 0, 0, 0);
      }
    __builtin_amdgcn_s_setprio(0);
  }

  // ---- epilogue: LDS-staged coalesced stores ----
  const float* bias; char* outp; int ocol0;
  if (NCOLS == 1024 || bcol < 1024) { bias = bias0; outp = (char*)out0; ocol0 = bcol; }
  else                              { bias = bias1; outp = (char*)out1; ocol0 = bcol - 1024; }

  constexpr int ESZ  = OUT_BF16 ? 2 : 4;
  constexpr int RPP  = OUT_BF16 ? 128 : 64;   // rows per pass (32 KB each)
  constexpr int NPAS = 128 / RPP;
  constexpr int ROWB = 128 * ESZ;             // bytes per tile row

  #pragma unroll
  for (int p = 0; p < NPAS; ++p) {
    if (NPAS == 1 || wr == p) {
      #pragma unroll
      for (int n = 0; n < 4; ++n) {
        int col = wc * 64 + n * 16 + lr;
        float bb = bias[ocol0 + col];
        #pragma unroll
        for (int m = 0; m < 4; ++m)
          #pragma unroll
          for (int r = 0; r < 4; ++r) {
            int rl = m * 16 + kg * 4 + r;
            int row = (NPAS == 1) ? (wr * 64 + rl) : rl;
            float v = acc[m][n][r] + bb;
            if (OUT_BF16) ((unsigned short*)smem)[row * 128 + col] = f2bf(v);
            else          ((float*)smem)[row * 128 + col] = v;
          }
      }
    }
    __syncthreads();
    #pragma unroll
    for (int i = 0; i < 8; ++i) {
      int off = i * 4096 + tid * 16;
      int row = off / ROWB, colb = off % ROWB;
      char* gp = outp + ((size_t)(brow + p * RPP + row) * 1024 + ocol0) * ESZ + colb;
      *(float4*)gp = *(const float4*)(smem + off);
    }
    if (p + 1 < NPAS) __syncthreads();
  }
}

// ---------------- per-sample 8x8 cross-head attention ------------------------
__global__ __launch_bounds__(256) void attn_k(const unsigned short* __restrict__ Q,
                                              const unsigned short* __restrict__ Kc,
                                              const unsigned short* __restrict__ V,
                                              unsigned short* __restrict__ ctx) {
  __shared__ __align__(16) unsigned short sm[4][3][NH][136];
  const int wid = threadIdx.x >> 6, lane = threadIdx.x & 63;
  const int b = (blockIdx.x << 2) + wid;

  const unsigned short* bases[3] = { Q + (size_t)b * DIMSZ,
                                     Kc + (size_t)b * DIMSZ,
                                     V + (size_t)b * DIMSZ };
  const int row = lane >> 3, ch = lane & 7;
  #pragma unroll
  for (int m = 0; m < 3; ++m) {
    ushort8v v0 = *(const ushort8v*)(bases[m] + row * HD + ch * 16);
    ushort8v v1 = *(const ushort8v*)(bases[m] + row * HD + ch * 16 + 8);
    *(ushort8v*)&sm[wid][m][row][ch * 16] = v0;
    *(ushort8v*)&sm[wid][m][row][ch * 16 + 8] = v1;
  }
  __syncthreads();

  const int h = lane >> 3, g = lane & 7;
  const unsigned short* qr = &sm[wid][0][h][0];
  const unsigned short* kr = &sm[wid][1][g][0];
  float s = 0.f;
  #pragma unroll
  for (int c = 0; c < 16; ++c) {
    ushort8v qv = *(const ushort8v*)(qr + c * 8);
    ushort8v kv = *(const ushort8v*)(kr + c * 8);
    #pragma unroll
    for (int j = 0; j < 8; ++j) s += bf2f(qv[j]) * bf2f(kv[j]);
  }
  s *= 0.088388347648318447f;

  float mx = s;
  #pragma unroll
  for (int o = 1; o < 8; o <<= 1) mx = fmaxf(mx, __shfl_xor(mx, o));
  float e = __expf(s - mx);
  float sum = e;
  #pragma unroll
  for (int o = 1; o < 8; o <<= 1) sum += __shfl_xor(sum, o);
  float attn = e / sum;

  const int h2 = lane >> 3, d0 = (lane & 7) * 16;
  float cacc[16];
  #pragma unroll
  for (int j = 0; j < 16; ++j) cacc[j] = 0.f;
  #pragma unroll
  for (int g2 = 0; g2 < 8; ++g2) {
    float a = __shfl(attn, (lane & 56) + g2);
    const unsigned short* vr = &sm[wid][2][g2][d0];
    ushort8v v0 = *(const ushort8v*)vr;
    ushort8v v1 = *(const ushort8v*)(vr + 8);
    #pragma unroll
    for (int j = 0; j < 8; ++j) {
      cacc[j]     += a * bf2f(v0[j]);
      cacc[8 + j] += a * bf2f(v1[j]);
    }
  }
  ushort8v o0, o1;
  #pragma unroll
  for (int j = 0; j < 8; ++j) { o0[j] = f2bf(cacc[j]); o1[j] = f2bf(cacc[8 + j]); }
  unsigned short* op = ctx + (size_t)b * DIMSZ + h2 * HD + d0;
  *(ushort8v*)op = o0;
  *(ushort8v*)(op + 8) = o1;
}

// ---------------- launcher ---------------------------------------------------
extern "C" void kernel_launch(void* const* d_in, const int* in_sizes, int n_in,
                              void* d_out, int out_size, void* d_ws, size_t ws_size,
                              hipStream_t stream) {
  const float* feat1 = (const float*)d_in[0];
  const float* feat2 = (const float*)d_in[1];
  const float* Wq = (const float*)d_in[2];
  const float* bq = (const float*)d_in[3];
  const float* Wk = (const float*)d_in[4];
  const float* bk = (const float*)d_in[5];
  const float* Wv = (const float*)d_in[6];
  const float* bv = (const float*)d_in[7];
  const float* Wo = (const float*)d_in[8];
  const float* bo = (const float*)d_in[9];
  float* out = (float*)d_out;

  const int M = B_ROWS;
  char* ws = (char*)d_ws;
  const size_t featB = (size_t)M * DIMSZ * 2;   // 32 MB per bf16 buffer
  const size_t wB = (size_t)DIMSZ * DIMSZ * 2;  // 2 MB per bf16 weight
  unsigned short* Qb  = (unsigned short*)(ws);
  unsigned short* Kb  = (unsigned short*)(ws + featB);
  unsigned short* Vb  = (unsigned short*)(ws + 2 * featB);
  unsigned short* ctx = (unsigned short*)(ws + 3 * featB);
  unsigned short* Wqt = (unsigned short*)(ws + 4 * featB);
  unsigned short* Wkt = (unsigned short*)(ws + 4 * featB + wB);   // Wkt,Wvt adjacent
  unsigned short* Wvt = (unsigned short*)(ws + 4 * featB + 2 * wB);
  unsigned short* Wot = (unsigned short*)(ws + 4 * featB + 3 * wB);

  transpose_cvt4_k<<<dim3(32, 32, 4), 256, 0, stream>>>(Wq, Wk, Wv, Wo,
                                                        Wqt, Wkt, Wvt, Wot);

  // Q: fp32-A fused cvt (1024 blocks); KV fused: N=2048 (2048 blocks)
  gemm9_k<1024, 1, 1><<<1024, 256, 0, stream>>>(feat1, Wqt, bq, bq, Qb, Qb);
  gemm9_k<2048, 1, 1><<<2048, 256, 0, stream>>>(feat2, Wkt, bk, bv, Kb, Vb);

  attn_k<<<M / 4, 256, 0, stream>>>(Qb, Kb, Vb, ctx);

  // output projection: bf16 A (ctx), fp32 out
  gemm9_k<1024, 0, 0><<<1024, 256, 0, stream>>>(ctx, Wot, bo, bo, out, out);
}

// Round 10
// 347.743 us; speedup vs baseline: 1.1062x; 1.1062x over previous
//
#include <hip/hip_runtime.h>
#include <cstdint>
#include <cstddef>

#define B_ROWS 16384
#define DIMSZ  1024
#define NH     8
#define HD     128
#define KDIM   1024

typedef __attribute__((ext_vector_type(8))) __bf16 bf16x8;
typedef __attribute__((ext_vector_type(4))) float f32x4;
typedef __attribute__((ext_vector_type(8))) unsigned short ushort8v;
typedef __attribute__((ext_vector_type(4))) unsigned short ushort4v;

__device__ __forceinline__ unsigned short f2bf(float f) {
  union { float f; unsigned int u; } x; x.f = f;
  unsigned int r = x.u + 0x7FFFu + ((x.u >> 16) & 1u);   // RNE
  return (unsigned short)(r >> 16);
}
__device__ __forceinline__ float bf2f(unsigned short h) {
  union { unsigned int u; float f; } x; x.u = ((unsigned int)h) << 16;
  return x.f;
}

__device__ __forceinline__ void gload_lds16(const void* g, void* l) {
  __builtin_amdgcn_global_load_lds(
      (__attribute__((address_space(1))) void*)(uintptr_t)g,
      (__attribute__((address_space(3))) void*)(uintptr_t)l, 16, 0, 0);
}

// ---------------- all 4 weight transposes, one launch ------------------------
__global__ __launch_bounds__(256) void transpose_cvt4_k(
    const float* __restrict__ W0, const float* __restrict__ W1,
    const float* __restrict__ W2, const float* __restrict__ W3,
    unsigned short* __restrict__ T0, unsigned short* __restrict__ T1,
    unsigned short* __restrict__ T2, unsigned short* __restrict__ T3) {
  const float* W; unsigned short* T;
  switch (blockIdx.z) {
    case 0: W = W0; T = T0; break;
    case 1: W = W1; T = T1; break;
    case 2: W = W2; T = T2; break;
    default: W = W3; T = T3; break;
  }
  __shared__ float tile[32][33];
  int bx = blockIdx.x * 32, by = blockIdx.y * 32;
  int tx = threadIdx.x & 31, ty = threadIdx.x >> 5;
  #pragma unroll
  for (int j = ty; j < 32; j += 8)
    tile[j][tx] = W[(size_t)(by + j) * DIMSZ + bx + tx];
  __syncthreads();
  #pragma unroll
  for (int j = ty; j < 32; j += 8)
    T[(size_t)(bx + j) * DIMSZ + by + tx] = f2bf(tile[tx][j]);
}

// ---------------- fused-cvt QKV GEMM (one dispatch, 3072 blocks) -------------
// blocks x<1024:  Q = feat1 @ Wqt^T + bq          (bcol = (x&7)*128)
// blocks x>=1024: K|V = feat2 @ Wkvt^T + bk|bv    (y=x-1024, bcol=(y&15)*128)
// BM=BN=128, BK=64, 4 waves, per-wave 64x64, acc[4][4]; single 32 KB LDS
// buffer, 2 __syncthreads/K-tile, 3 blocks/CU.  A is fp32: reg-staged
// (global float4 -> f2bf -> swizzled ds_write_b64).  loadA is PINNED with
// sched_barrier(0) (R9 lesson: without the pin the scheduler sinks the loads
// to just before writeA to save VGPRs, exposing full load latency every
// K-tile -> MfmaUtil 14%, 2.9x slowdown; VGPR staying at 84 was the tell).
// B via gload_lds with inverse-swizzled source.  0-conflict XOR swizzle
// c' = c ^ (row&7) on 16B chunks.  T1 XCD swizzle.  LDS-staged C stores.
// NOTE: __launch_bounds__ MUST stay (256,3): (256,4) caps VGPR at 64 ->
// accumulator spills -> 455MB scratch traffic, 2.4x slower (R6 regression).
__global__ __launch_bounds__(256, 3) void qkv_k(
    const float* __restrict__ feat1, const float* __restrict__ feat2,
    const unsigned short* __restrict__ Wqt, const unsigned short* __restrict__ Wkvt,
    const float* __restrict__ bq, const float* __restrict__ bk,
    const float* __restrict__ bv,
    unsigned short* __restrict__ Qb, unsigned short* __restrict__ Kb,
    unsigned short* __restrict__ Vb) {
  constexpr int NWG = 3072;
  constexpr int NKT = KDIM / 64;   // 16

  __shared__ __align__(16) char smem[32768];
  char* Asm = smem;
  char* Bsm = smem + 16384;

  const int tid = threadIdx.x;
  const int lane = tid & 63;
  const int lr = lane & 15, kg = lane >> 4;
  const int wid = tid >> 6;
  const int wr = wid >> 1, wc = wid & 1;
  const int swz = lr & 7;

  const int x = ((int)blockIdx.x % 8) * (NWG / 8) + (int)blockIdx.x / 8;
  const float* Af; const unsigned short* Bt; int bcol, brow;
  if (x < 1024) { Af = feat1; Bt = Wqt;  bcol = (x & 7) * 128;  brow = (x >> 3) * 128; }
  else { int y = x - 1024; Af = feat2; Bt = Wkvt; bcol = (y & 15) * 128; brow = (y >> 4) * 128; }
  Af += (size_t)brow * KDIM;
  const char* Bb = (const char*)(Bt + (size_t)bcol * KDIM);

  // B staging: linear LDS dest, inverse-swizzled global source
  int soff[4];
  #pragma unroll
  for (int j = 0; j < 4; ++j) {
    int D = j * 4096 + tid * 16;
    int row = D >> 7, c = (D >> 4) & 7;
    soff[j] = row * 2048 + ((c ^ (row & 7)) << 4);
  }
  auto stageB = [&](int t) {
    #pragma unroll
    for (int j = 0; j < 4; ++j)
      gload_lds16(Bb + (size_t)soff[j] + t * 128, Bsm + j * 4096 + tid * 16);
  };

  // A: fp32 reg-staging
  const int agbase = (tid >> 4) * KDIM + (tid & 15) * 4;   // floats
  const int albase = (tid >> 4) * 128 +
                     (((((tid & 15) >> 1) ^ ((tid >> 4) & 7))) << 4) +
                     (tid & 1) * 8;
  f32x4 gA[8];
  auto loadA = [&](int t) {
    #pragma unroll
    for (int j = 0; j < 8; ++j)
      gA[j] = *(const f32x4*)(Af + (size_t)j * 16 * KDIM + agbase + t * 64);
    __builtin_amdgcn_sched_barrier(0);   // PIN: loads may not sink past here
  };
  auto writeA = [&]() {
    #pragma unroll
    for (int j = 0; j < 8; ++j) {
      ushort4v h;
      h[0] = f2bf(gA[j][0]); h[1] = f2bf(gA[j][1]);
      h[2] = f2bf(gA[j][2]); h[3] = f2bf(gA[j][3]);
      *(ushort4v*)(Asm + j * 2048 + albase) = h;
    }
  };

  f32x4 acc[4][4] = {};

  // prologue: A(0) regs -> LDS; B(0) async; A(1) regs in flight
  loadA(0);
  stageB(0);
  writeA();          // waits gA(0) only (vmcnt leaves B in flight)
  loadA(1);

  #pragma unroll 1
  for (int t = 0; t < NKT; ++t) {
    __syncthreads();   // stage(t) complete

    bf16x8 af[4][2], bfr[4][2];
    #pragma unroll
    for (int m = 0; m < 4; ++m) {
      int row = wr * 64 + m * 16 + lr;
      #pragma unroll
      for (int kk = 0; kk < 2; ++kk)
        af[m][kk] = *(const bf16x8*)(Asm + row * 128 + (((kk * 4 + kg) ^ swz) << 4));
    }
    #pragma unroll
    for (int n = 0; n < 4; ++n) {
      int row = wc * 64 + n * 16 + lr;
      #pragma unroll
      for (int kk = 0; kk < 2; ++kk)
        bfr[n][kk] = *(const bf16x8*)(Bsm + row * 128 + (((kk * 4 + kg) ^ swz) << 4));
    }
    __syncthreads();   // all waves' reads done -> buffers free

    if (t + 1 < NKT) {
      stageB(t + 1);                  // independent async loads first
      writeA();                       // gA(t+1) -> LDS (loads issued last iter)
      if (t + 2 < NKT) loadA(t + 2);  // pinned issue; consumed next iter
    }

    __builtin_amdgcn_s_setprio(1);
    #pragma unroll
    for (int m = 0; m < 4; ++m)
      #pragma unroll
      for (int n = 0; n < 4; ++n) {
        acc[m][n] = __builtin_amdgcn_mfma_f32_16x16x32_bf16(af[m][0], bfr[n][0], acc[m][n], 0, 0, 0);
        acc[m][n] = __builtin_amdgcn_mfma_f32_16x16x32_bf16(af[m][1], bfr[n][1], acc[m][n], 0, 0, 0);
      }
    __builtin_amdgcn_s_setprio(0);
  }

  // epilogue: bias + LDS-staged coalesced bf16 stores
  const float* bias; unsigned short* outp; int ocol0;
  if (x < 1024)          { bias = bq; outp = Qb; ocol0 = bcol; }
  else if (bcol < 1024)  { bias = bk; outp = Kb; ocol0 = bcol; }
  else                   { bias = bv; outp = Vb; ocol0 = bcol - 1024; }

  #pragma unroll
  for (int n = 0; n < 4; ++n) {
    int col = wc * 64 + n * 16 + lr;
    float bb = bias[ocol0 + col];
    #pragma unroll
    for (int m = 0; m < 4; ++m)
      #pragma unroll
      for (int r = 0; r < 4; ++r) {
        int row = wr * 64 + m * 16 + kg * 4 + r;
        ((unsigned short*)smem)[row * 128 + col] = f2bf(acc[m][n][r] + bb);
      }
  }
  __syncthreads();
  #pragma unroll
  for (int i = 0; i < 8; ++i) {
    int off = i * 4096 + tid * 16;
    int row = off >> 8, colb = off & 255;
    char* gp = (char*)outp + ((size_t)(brow + row) * 1024 + ocol0) * 2 + colb;
    *(float4*)gp = *(const float4*)(smem + off);
  }
}

// ---------------- O-projection GEMM (bf16 A via gload_lds, fp32 out) ---------
__global__ __launch_bounds__(256, 3) void gemmo_k(
    const unsigned short* __restrict__ A,
    const unsigned short* __restrict__ Bt,
    const float* __restrict__ bias, float* __restrict__ out) {
  constexpr int NWG = 1024;
  constexpr int NKT = KDIM / 64;

  __shared__ __align__(16) char smem[32768];
  char* Asm = smem;
  char* Bsm = smem + 16384;

  const int tid = threadIdx.x;
  const int lane = tid & 63;
  const int lr = lane & 15, kg = lane >> 4;
  const int wid = tid >> 6;
  const int wr = wid >> 1, wc = wid & 1;
  const int swz = lr & 7;

  const int x = ((int)blockIdx.x % 8) * (NWG / 8) + (int)blockIdx.x / 8;
  const int bcol = (x & 7) * 128;
  const int brow = (x >> 3) * 128;

  const char* Ab = (const char*)(A + (size_t)brow * KDIM);
  const char* Bb = (const char*)(Bt + (size_t)bcol * KDIM);

  int soff[4];
  #pragma unroll
  for (int j = 0; j < 4; ++j) {
    int D = j * 4096 + tid * 16;
    int row = D >> 7, c = (D >> 4) & 7;
    soff[j] = row * 2048 + ((c ^ (row & 7)) << 4);
  }
  auto stage = [&](int t) {
    #pragma unroll
    for (int j = 0; j < 4; ++j) {
      gload_lds16(Ab + (size_t)soff[j] + t * 128, Asm + j * 4096 + tid * 16);
      gload_lds16(Bb + (size_t)soff[j] + t * 128, Bsm + j * 4096 + tid * 16);
    }
  };

  f32x4 acc[4][4] = {};
  stage(0);

  #pragma unroll 1
  for (int t = 0; t < NKT; ++t) {
    __syncthreads();

    bf16x8 af[4][2], bfr[4][2];
    #pragma unroll
    for (int m = 0; m < 4; ++m) {
      int row = wr * 64 + m * 16 + lr;
      #pragma unroll
      for (int kk = 0; kk < 2; ++kk)
        af[m][kk] = *(const bf16x8*)(Asm + row * 128 + (((kk * 4 + kg) ^ swz) << 4));
    }
    #pragma unroll
    for (int n = 0; n < 4; ++n) {
      int row = wc * 64 + n * 16 + lr;
      #pragma unroll
      for (int kk = 0; kk < 2; ++kk)
        bfr[n][kk] = *(const bf16x8*)(Bsm + row * 128 + (((kk * 4 + kg) ^ swz) << 4));
    }
    __syncthreads();

    if (t + 1 < NKT) stage(t + 1);

    __builtin_amdgcn_s_setprio(1);
    #pragma unroll
    for (int m = 0; m < 4; ++m)
      #pragma unroll
      for (int n = 0; n < 4; ++n) {
        acc[m][n] = __builtin_amdgcn_mfma_f32_16x16x32_bf16(af[m][0], bfr[n][0], acc[m][n], 0, 0, 0);
        acc[m][n] = __builtin_amdgcn_mfma_f32_16x16x32_bf16(af[m][1], bfr[n][1], acc[m][n], 0, 0, 0);
      }
    __builtin_amdgcn_s_setprio(0);
  }

  // epilogue: two 64-row passes through LDS, coalesced fp32 stores
  #pragma unroll
  for (int p = 0; p < 2; ++p) {
    if (wr == p) {
      #pragma unroll
      for (int n = 0; n < 4; ++n) {
        int col = wc * 64 + n * 16 + lr;
        float bb = bias[bcol + col];
        #pragma unroll
        for (int m = 0; m < 4; ++m)
          #pragma unroll
          for (int r = 0; r < 4; ++r) {
            int row = m * 16 + kg * 4 + r;
            ((float*)smem)[row * 128 + col] = acc[m][n][r] + bb;
          }
      }
    }
    __syncthreads();
    #pragma unroll
    for (int i = 0; i < 8; ++i) {
      int off = i * 4096 + tid * 16;
      int row = off >> 9, colb = off & 511;
      char* gp = (char*)out + ((size_t)(brow + p * 64 + row) * 1024 + bcol) * 4 + colb;
      *(float4*)gp = *(const float4*)(smem + off);
    }
    if (p == 0) __syncthreads();
  }
}

// ---------------- per-sample 8x8 cross-head attention ------------------------
__global__ __launch_bounds__(256) void attn_k(const unsigned short* __restrict__ Q,
                                              const unsigned short* __restrict__ Kc,
                                              const unsigned short* __restrict__ V,
                                              unsigned short* __restrict__ ctx) {
  __shared__ __align__(16) unsigned short sm[4][3][NH][136];
  const int wid = threadIdx.x >> 6, lane = threadIdx.x & 63;
  const int b = (blockIdx.x << 2) + wid;

  const unsigned short* bases[3] = { Q + (size_t)b * DIMSZ,
                                     Kc + (size_t)b * DIMSZ,
                                     V + (size_t)b * DIMSZ };
  const int row = lane >> 3, ch = lane & 7;
  #pragma unroll
  for (int m = 0; m < 3; ++m) {
    ushort8v v0 = *(const ushort8v*)(bases[m] + row * HD + ch * 16);
    ushort8v v1 = *(const ushort8v*)(bases[m] + row * HD + ch * 16 + 8);
    *(ushort8v*)&sm[wid][m][row][ch * 16] = v0;
    *(ushort8v*)&sm[wid][m][row][ch * 16 + 8] = v1;
  }
  __syncthreads();

  const int h = lane >> 3, g = lane & 7;
  const unsigned short* qr = &sm[wid][0][h][0];
  const unsigned short* kr = &sm[wid][1][g][0];
  float s = 0.f;
  #pragma unroll
  for (int c = 0; c < 16; ++c) {
    ushort8v qv = *(const ushort8v*)(qr + c * 8);
    ushort8v kv = *(const ushort8v*)(kr + c * 8);
    #pragma unroll
    for (int j = 0; j < 8; ++j) s += bf2f(qv[j]) * bf2f(kv[j]);
  }
  s *= 0.088388347648318447f;

  float mx = s;
  #pragma unroll
  for (int o = 1; o < 8; o <<= 1) mx = fmaxf(mx, __shfl_xor(mx, o));
  float e = __expf(s - mx);
  float sum = e;
  #pragma unroll
  for (int o = 1; o < 8; o <<= 1) sum += __shfl_xor(sum, o);
  float attn = e / sum;

  const int h2 = lane >> 3, d0 = (lane & 7) * 16;
  float cacc[16];
  #pragma unroll
  for (int j = 0; j < 16; ++j) cacc[j] = 0.f;
  #pragma unroll
  for (int g2 = 0; g2 < 8; ++g2) {
    float a = __shfl(attn, (lane & 56) + g2);
    const unsigned short* vr = &sm[wid][2][g2][d0];
    ushort8v v0 = *(const ushort8v*)vr;
    ushort8v v1 = *(const ushort8v*)(vr + 8);
    #pragma unroll
    for (int j = 0; j < 8; ++j) {
      cacc[j]     += a * bf2f(v0[j]);
      cacc[8 + j] += a * bf2f(v1[j]);
    }
  }
  ushort8v o0, o1;
  #pragma unroll
  for (int j = 0; j < 8; ++j) { o0[j] = f2bf(cacc[j]); o1[j] = f2bf(cacc[8 + j]); }
  unsigned short* op = ctx + (size_t)b * DIMSZ + h2 * HD + d0;
  *(ushort8v*)op = o0;
  *(ushort8v*)(op + 8) = o1;
}

// ---------------- launcher ---------------------------------------------------
extern "C" void kernel_launch(void* const* d_in, const int* in_sizes, int n_in,
                              void* d_out, int out_size, void* d_ws, size_t ws_size,
                              hipStream_t stream) {
  const float* feat1 = (const float*)d_in[0];
  const float* feat2 = (const float*)d_in[1];
  const float* Wq = (const float*)d_in[2];
  const float* bq = (const float*)d_in[3];
  const float* Wk = (const float*)d_in[4];
  const float* bk = (const float*)d_in[5];
  const float* Wv = (const float*)d_in[6];
  const float* bv = (const float*)d_in[7];
  const float* Wo = (const float*)d_in[8];
  const float* bo = (const float*)d_in[9];
  float* out = (float*)d_out;

  const int M = B_ROWS;
  char* ws = (char*)d_ws;
  const size_t featB = (size_t)M * DIMSZ * 2;   // 32 MB per bf16 buffer
  const size_t wB = (size_t)DIMSZ * DIMSZ * 2;  // 2 MB per bf16 weight
  unsigned short* Qb  = (unsigned short*)(ws);
  unsigned short* Kb  = (unsigned short*)(ws + featB);
  unsigned short* Vb  = (unsigned short*)(ws + 2 * featB);
  unsigned short* ctx = (unsigned short*)(ws + 3 * featB);
  unsigned short* Wqt = (unsigned short*)(ws + 4 * featB);
  unsigned short* Wkt = (unsigned short*)(ws + 4 * featB + wB);   // Wkt,Wvt adjacent
  unsigned short* Wvt = (unsigned short*)(ws + 4 * featB + 2 * wB);
  unsigned short* Wot = (unsigned short*)(ws + 4 * featB + 3 * wB);

  transpose_cvt4_k<<<dim3(32, 32, 4), 256, 0, stream>>>(Wq, Wk, Wv, Wo,
                                                        Wqt, Wkt, Wvt, Wot);

  // fused-cvt Q+K+V in one dispatch (3072 blocks)
  qkv_k<<<3072, 256, 0, stream>>>(feat1, feat2, Wqt, Wkt,
                                  bq, bk, bv, Qb, Kb, Vb);

  attn_k<<<M / 4, 256, 0, stream>>>(Qb, Kb, Vb, ctx);

  // output projection: bf16 A (ctx), fp32 out
  gemmo_k<<<1024, 256, 0, stream>>>(ctx, Wot, bo, out);
}

// Round 11
// 209.595 us; speedup vs baseline: 1.8354x; 1.6591x over previous
//
#include <hip/hip_runtime.h>
#include <cstdint>
#include <cstddef>

#define B_ROWS 16384
#define DIMSZ  1024
#define NH     8
#define HD     128
#define KDIM   1024

typedef __attribute__((ext_vector_type(8))) __bf16 bf16x8;
typedef __attribute__((ext_vector_type(4))) float f32x4;
typedef __attribute__((ext_vector_type(8))) unsigned short ushort8v;

__device__ __forceinline__ unsigned short f2bf(float f) {
  union { float f; unsigned int u; } x; x.f = f;
  unsigned int r = x.u + 0x7FFFu + ((x.u >> 16) & 1u);   // RNE
  return (unsigned short)(r >> 16);
}
__device__ __forceinline__ float bf2f(unsigned short h) {
  union { unsigned int u; float f; } x; x.u = ((unsigned int)h) << 16;
  return x.f;
}

__device__ __forceinline__ void gload_lds16(const void* g, void* l) {
  __builtin_amdgcn_global_load_lds(
      (__attribute__((address_space(1))) void*)(uintptr_t)g,
      (__attribute__((address_space(3))) void*)(uintptr_t)l, 16, 0, 0);
}

// ---------------- prep: fp32->bf16 feature cvt + 4 weight transposes ---------
// blocks [0, 16384): cvt (8 elems/thread, feat1 then feat2)
// blocks [16384, 20480): 32x32 transpose tiles of the 4 weights
__global__ __launch_bounds__(256) void prep_k(
    const float* __restrict__ feat1, const float* __restrict__ feat2,
    unsigned short* __restrict__ f1b, unsigned short* __restrict__ f2b,
    const float* __restrict__ W0, const float* __restrict__ W1,
    const float* __restrict__ W2, const float* __restrict__ W3,
    unsigned short* __restrict__ T0, unsigned short* __restrict__ T1,
    unsigned short* __restrict__ T2, unsigned short* __restrict__ T3) {
  __shared__ float tile[32][33];
  const int bid = blockIdx.x;
  if (bid < 16384) {
    const int n8each = B_ROWS * DIMSZ / 8;   // 2097152
    int i = bid * 256 + threadIdx.x;
    const float* src; unsigned short* dst; int j;
    if (i < n8each) { src = feat1; dst = f1b; j = i; }
    else            { src = feat2; dst = f2b; j = i - n8each; }
    const float4* p = (const float4*)src + 2 * (size_t)j;
    float4 x = p[0], y = p[1];
    ushort8v o;
    o[0] = f2bf(x.x); o[1] = f2bf(x.y); o[2] = f2bf(x.z); o[3] = f2bf(x.w);
    o[4] = f2bf(y.x); o[5] = f2bf(y.y); o[6] = f2bf(y.z); o[7] = f2bf(y.w);
    *(ushort8v*)(dst + 8 * (size_t)j) = o;
  } else {
    int r = bid - 16384;
    int z = r >> 10, rest = r & 1023;
    const float* W; unsigned short* T;
    switch (z) {
      case 0: W = W0; T = T0; break;
      case 1: W = W1; T = T1; break;
      case 2: W = W2; T = T2; break;
      default: W = W3; T = T3; break;
    }
    int bx = (rest & 31) * 32, by = (rest >> 5) * 32;
    int tx = threadIdx.x & 31, ty = threadIdx.x >> 5;
    #pragma unroll
    for (int j = ty; j < 32; j += 8)
      tile[j][tx] = W[(size_t)(by + j) * DIMSZ + bx + tx];
    __syncthreads();
    #pragma unroll
    for (int j = ty; j < 32; j += 8)
      T[(size_t)(bx + j) * DIMSZ + by + tx] = f2bf(tile[tx][j]);
  }
}

// ---------------- merged QKV GEMM (one dispatch, 3072 blocks) ----------------
// blocks x<1024:  Q = f1b @ Wqt^T + bq      (bcol=(x&7)*128, brow=(x>>3)*128)
// blocks x>=1024: K|V = f2b @ Wkvt^T + bk|bv (y=x-1024, bcol=(y&15)*128)
// R5-proven structure: BM=BN=128, BK=64, 4 waves, per-wave 64x64, acc[4][4];
// single 32 KB LDS buffer, 2 __syncthreads/K-tile, gload_lds for BOTH
// operands (R8-R10 lesson: reg-staged A cannot be made to overlap at HIP
// level -- scheduler sinks the loads; gload_lds queue overlaps naturally);
// stage(t+1) issued after the read-done barrier, before the 32-MFMA cluster;
// 3 blocks/CU cross-block overlap covers the barrier drains.  0-conflict XOR
// swizzle c' = c ^ (row&7) on 16B chunks, inverse-permuted global source.
// T1 XCD swizzle.  LDS-staged coalesced bf16 C stores.
// NOTE: __launch_bounds__ MUST stay (256,3): (256,4) caps VGPR at 64 ->
// accumulator spills -> 455MB scratch traffic, 2.4x slower (R6 regression).
__global__ __launch_bounds__(256, 3) void qkv_k(
    const unsigned short* __restrict__ f1b, const unsigned short* __restrict__ f2b,
    const unsigned short* __restrict__ Wqt, const unsigned short* __restrict__ Wkvt,
    const float* __restrict__ bq, const float* __restrict__ bk,
    const float* __restrict__ bv,
    unsigned short* __restrict__ Qb, unsigned short* __restrict__ Kb,
    unsigned short* __restrict__ Vb) {
  constexpr int NWG = 3072;
  constexpr int NKT = KDIM / 64;   // 16

  __shared__ __align__(16) char smem[32768];
  char* Asm = smem;
  char* Bsm = smem + 16384;

  const int tid = threadIdx.x;
  const int lane = tid & 63;
  const int lr = lane & 15, kg = lane >> 4;
  const int wid = tid >> 6;
  const int wr = wid >> 1, wc = wid & 1;
  const int swz = lr & 7;

  const int x = ((int)blockIdx.x % 8) * (NWG / 8) + (int)blockIdx.x / 8;
  const unsigned short* A; const unsigned short* Bt; int bcol, brow;
  if (x < 1024) { A = f1b; Bt = Wqt;  bcol = (x & 7) * 128;  brow = (x >> 3) * 128; }
  else { int y = x - 1024; A = f2b; Bt = Wkvt; bcol = (y & 15) * 128; brow = (y >> 4) * 128; }

  const char* Ab = (const char*)(A + (size_t)brow * KDIM);
  const char* Bb = (const char*)(Bt + (size_t)bcol * KDIM);

  int soff[4];
  #pragma unroll
  for (int j = 0; j < 4; ++j) {
    int D = j * 4096 + tid * 16;
    int row = D >> 7, c = (D >> 4) & 7;
    soff[j] = row * 2048 + ((c ^ (row & 7)) << 4);
  }
  auto stage = [&](int t) {
    #pragma unroll
    for (int j = 0; j < 4; ++j) {
      gload_lds16(Ab + (size_t)soff[j] + t * 128, Asm + j * 4096 + tid * 16);
      gload_lds16(Bb + (size_t)soff[j] + t * 128, Bsm + j * 4096 + tid * 16);
    }
  };

  f32x4 acc[4][4] = {};
  stage(0);

  #pragma unroll 1
  for (int t = 0; t < NKT; ++t) {
    __syncthreads();   // stage(t) landed

    bf16x8 af[4][2], bfr[4][2];
    #pragma unroll
    for (int m = 0; m < 4; ++m) {
      int row = wr * 64 + m * 16 + lr;
      #pragma unroll
      for (int kk = 0; kk < 2; ++kk)
        af[m][kk] = *(const bf16x8*)(Asm + row * 128 + (((kk * 4 + kg) ^ swz) << 4));
    }
    #pragma unroll
    for (int n = 0; n < 4; ++n) {
      int row = wc * 64 + n * 16 + lr;
      #pragma unroll
      for (int kk = 0; kk < 2; ++kk)
        bfr[n][kk] = *(const bf16x8*)(Bsm + row * 128 + (((kk * 4 + kg) ^ swz) << 4));
    }
    __syncthreads();   // all waves' reads done -> buffer free

    if (t + 1 < NKT) stage(t + 1);   // async queue; latency hides under MFMA

    __builtin_amdgcn_s_setprio(1);
    #pragma unroll
    for (int m = 0; m < 4; ++m)
      #pragma unroll
      for (int n = 0; n < 4; ++n) {
        acc[m][n] = __builtin_amdgcn_mfma_f32_16x16x32_bf16(af[m][0], bfr[n][0], acc[m][n], 0, 0, 0);
        acc[m][n] = __builtin_amdgcn_mfma_f32_16x16x32_bf16(af[m][1], bfr[n][1], acc[m][n], 0, 0, 0);
      }
    __builtin_amdgcn_s_setprio(0);
  }

  // epilogue: bias + LDS-staged coalesced bf16 stores
  const float* bias; unsigned short* outp; int ocol0;
  if (x < 1024)         { bias = bq; outp = Qb; ocol0 = bcol; }
  else if (bcol < 1024) { bias = bk; outp = Kb; ocol0 = bcol; }
  else                  { bias = bv; outp = Vb; ocol0 = bcol - 1024; }

  #pragma unroll
  for (int n = 0; n < 4; ++n) {
    int col = wc * 64 + n * 16 + lr;
    float bb = bias[ocol0 + col];
    #pragma unroll
    for (int m = 0; m < 4; ++m)
      #pragma unroll
      for (int r = 0; r < 4; ++r) {
        int row = wr * 64 + m * 16 + kg * 4 + r;
        ((unsigned short*)smem)[row * 128 + col] = f2bf(acc[m][n][r] + bb);
      }
  }
  __syncthreads();
  #pragma unroll
  for (int i = 0; i < 8; ++i) {
    int off = i * 4096 + tid * 16;
    int row = off >> 8, colb = off & 255;
    char* gp = (char*)outp + ((size_t)(brow + row) * 1024 + ocol0) * 2 + colb;
    *(float4*)gp = *(const float4*)(smem + off);
  }
}

// ---------------- O-projection GEMM (bf16 A via gload_lds, fp32 out) ---------
__global__ __launch_bounds__(256, 3) void gemmo_k(
    const unsigned short* __restrict__ A,
    const unsigned short* __restrict__ Bt,
    const float* __restrict__ bias, float* __restrict__ out) {
  constexpr int NWG = 1024;
  constexpr int NKT = KDIM / 64;

  __shared__ __align__(16) char smem[32768];
  char* Asm = smem;
  char* Bsm = smem + 16384;

  const int tid = threadIdx.x;
  const int lane = tid & 63;
  const int lr = lane & 15, kg = lane >> 4;
  const int wid = tid >> 6;
  const int wr = wid >> 1, wc = wid & 1;
  const int swz = lr & 7;

  const int x = ((int)blockIdx.x % 8) * (NWG / 8) + (int)blockIdx.x / 8;
  const int bcol = (x & 7) * 128;
  const int brow = (x >> 3) * 128;

  const char* Ab = (const char*)(A + (size_t)brow * KDIM);
  const char* Bb = (const char*)(Bt + (size_t)bcol * KDIM);

  int soff[4];
  #pragma unroll
  for (int j = 0; j < 4; ++j) {
    int D = j * 4096 + tid * 16;
    int row = D >> 7, c = (D >> 4) & 7;
    soff[j] = row * 2048 + ((c ^ (row & 7)) << 4);
  }
  auto stage = [&](int t) {
    #pragma unroll
    for (int j = 0; j < 4; ++j) {
      gload_lds16(Ab + (size_t)soff[j] + t * 128, Asm + j * 4096 + tid * 16);
      gload_lds16(Bb + (size_t)soff[j] + t * 128, Bsm + j * 4096 + tid * 16);
    }
  };

  f32x4 acc[4][4] = {};
  stage(0);

  #pragma unroll 1
  for (int t = 0; t < NKT; ++t) {
    __syncthreads();

    bf16x8 af[4][2], bfr[4][2];
    #pragma unroll
    for (int m = 0; m < 4; ++m) {
      int row = wr * 64 + m * 16 + lr;
      #pragma unroll
      for (int kk = 0; kk < 2; ++kk)
        af[m][kk] = *(const bf16x8*)(Asm + row * 128 + (((kk * 4 + kg) ^ swz) << 4));
    }
    #pragma unroll
    for (int n = 0; n < 4; ++n) {
      int row = wc * 64 + n * 16 + lr;
      #pragma unroll
      for (int kk = 0; kk < 2; ++kk)
        bfr[n][kk] = *(const bf16x8*)(Bsm + row * 128 + (((kk * 4 + kg) ^ swz) << 4));
    }
    __syncthreads();

    if (t + 1 < NKT) stage(t + 1);

    __builtin_amdgcn_s_setprio(1);
    #pragma unroll
    for (int m = 0; m < 4; ++m)
      #pragma unroll
      for (int n = 0; n < 4; ++n) {
        acc[m][n] = __builtin_amdgcn_mfma_f32_16x16x32_bf16(af[m][0], bfr[n][0], acc[m][n], 0, 0, 0);
        acc[m][n] = __builtin_amdgcn_mfma_f32_16x16x32_bf16(af[m][1], bfr[n][1], acc[m][n], 0, 0, 0);
      }
    __builtin_amdgcn_s_setprio(0);
  }

  // epilogue: two 64-row passes through LDS, coalesced fp32 stores
  #pragma unroll
  for (int p = 0; p < 2; ++p) {
    if (wr == p) {
      #pragma unroll
      for (int n = 0; n < 4; ++n) {
        int col = wc * 64 + n * 16 + lr;
        float bb = bias[bcol + col];
        #pragma unroll
        for (int m = 0; m < 4; ++m)
          #pragma unroll
          for (int r = 0; r < 4; ++r) {
            int row = m * 16 + kg * 4 + r;
            ((float*)smem)[row * 128 + col] = acc[m][n][r] + bb;
          }
      }
    }
    __syncthreads();
    #pragma unroll
    for (int i = 0; i < 8; ++i) {
      int off = i * 4096 + tid * 16;
      int row = off >> 9, colb = off & 511;
      char* gp = (char*)out + ((size_t)(brow + p * 64 + row) * 1024 + bcol) * 4 + colb;
      *(float4*)gp = *(const float4*)(smem + off);
    }
    if (p == 0) __syncthreads();
  }
}

// ---------------- per-sample 8x8 cross-head attention ------------------------
__global__ __launch_bounds__(256) void attn_k(const unsigned short* __restrict__ Q,
                                              const unsigned short* __restrict__ Kc,
                                              const unsigned short* __restrict__ V,
                                              unsigned short* __restrict__ ctx) {
  __shared__ __align__(16) unsigned short sm[4][3][NH][136];
  const int wid = threadIdx.x >> 6, lane = threadIdx.x & 63;
  const int b = (blockIdx.x << 2) + wid;

  const unsigned short* bases[3] = { Q + (size_t)b * DIMSZ,
                                     Kc + (size_t)b * DIMSZ,
                                     V + (size_t)b * DIMSZ };
  const int row = lane >> 3, ch = lane & 7;
  #pragma unroll
  for (int m = 0; m < 3; ++m) {
    ushort8v v0 = *(const ushort8v*)(bases[m] + row * HD + ch * 16);
    ushort8v v1 = *(const ushort8v*)(bases[m] + row * HD + ch * 16 + 8);
    *(ushort8v*)&sm[wid][m][row][ch * 16] = v0;
    *(ushort8v*)&sm[wid][m][row][ch * 16 + 8] = v1;
  }
  __syncthreads();

  const int h = lane >> 3, g = lane & 7;
  const unsigned short* qr = &sm[wid][0][h][0];
  const unsigned short* kr = &sm[wid][1][g][0];
  float s = 0.f;
  #pragma unroll
  for (int c = 0; c < 16; ++c) {
    ushort8v qv = *(const ushort8v*)(qr + c * 8);
    ushort8v kv = *(const ushort8v*)(kr + c * 8);
    #pragma unroll
    for (int j = 0; j < 8; ++j) s += bf2f(qv[j]) * bf2f(kv[j]);
  }
  s *= 0.088388347648318447f;

  float mx = s;
  #pragma unroll
  for (int o = 1; o < 8; o <<= 1) mx = fmaxf(mx, __shfl_xor(mx, o));
  float e = __expf(s - mx);
  float sum = e;
  #pragma unroll
  for (int o = 1; o < 8; o <<= 1) sum += __shfl_xor(sum, o);
  float attn = e / sum;

  const int h2 = lane >> 3, d0 = (lane & 7) * 16;
  float cacc[16];
  #pragma unroll
  for (int j = 0; j < 16; ++j) cacc[j] = 0.f;
  #pragma unroll
  for (int g2 = 0; g2 < 8; ++g2) {
    float a = __shfl(attn, (lane & 56) + g2);
    const unsigned short* vr = &sm[wid][2][g2][d0];
    ushort8v v0 = *(const ushort8v*)vr;
    ushort8v v1 = *(const ushort8v*)(vr + 8);
    #pragma unroll
    for (int j = 0; j < 8; ++j) {
      cacc[j]     += a * bf2f(v0[j]);
      cacc[8 + j] += a * bf2f(v1[j]);
    }
  }
  ushort8v o0, o1;
  #pragma unroll
  for (int j = 0; j < 8; ++j) { o0[j] = f2bf(cacc[j]); o1[j] = f2bf(cacc[8 + j]); }
  unsigned short* op = ctx + (size_t)b * DIMSZ + h2 * HD + d0;
  *(ushort8v*)op = o0;
  *(ushort8v*)(op + 8) = o1;
}

// ---------------- launcher ---------------------------------------------------
extern "C" void kernel_launch(void* const* d_in, const int* in_sizes, int n_in,
                              void* d_out, int out_size, void* d_ws, size_t ws_size,
                              hipStream_t stream) {
  const float* feat1 = (const float*)d_in[0];
  const float* feat2 = (const float*)d_in[1];
  const float* Wq = (const float*)d_in[2];
  const float* bq = (const float*)d_in[3];
  const float* Wk = (const float*)d_in[4];
  const float* bk = (const float*)d_in[5];
  const float* Wv = (const float*)d_in[6];
  const float* bv = (const float*)d_in[7];
  const float* Wo = (const float*)d_in[8];
  const float* bo = (const float*)d_in[9];
  float* out = (float*)d_out;

  const int M = B_ROWS;
  char* ws = (char*)d_ws;
  const size_t featB = (size_t)M * DIMSZ * 2;   // 32 MB per bf16 buffer
  const size_t wB = (size_t)DIMSZ * DIMSZ * 2;  // 2 MB per bf16 weight
  unsigned short* f1b = (unsigned short*)(ws);              // ctx aliases later
  unsigned short* f2b = (unsigned short*)(ws + featB);
  unsigned short* Qb  = (unsigned short*)(ws + 2 * featB);
  unsigned short* Kb  = (unsigned short*)(ws + 3 * featB);
  unsigned short* Vb  = (unsigned short*)(ws + 4 * featB);
  unsigned short* Wqt = (unsigned short*)(ws + 5 * featB);
  unsigned short* Wkt = (unsigned short*)(ws + 5 * featB + wB);   // Wkt,Wvt adjacent
  unsigned short* Wvt = (unsigned short*)(ws + 5 * featB + 2 * wB);
  unsigned short* Wot = (unsigned short*)(ws + 5 * featB + 3 * wB);
  unsigned short* ctx = f1b;   // f1b dead after the QKV dispatch

  // prep: both feature cvts + all 4 weight transposes, one dispatch
  prep_k<<<20480, 256, 0, stream>>>(feat1, feat2, f1b, f2b,
                                    Wq, Wk, Wv, Wo, Wqt, Wkt, Wvt, Wot);

  // merged Q+K+V GEMM (3072 blocks)
  qkv_k<<<3072, 256, 0, stream>>>(f1b, f2b, Wqt, Wkt,
                                  bq, bk, bv, Qb, Kb, Vb);

  attn_k<<<M / 4, 256, 0, stream>>>(Qb, Kb, Vb, ctx);

  // output projection: bf16 A (ctx), fp32 out
  gemmo_k<<<1024, 256, 0, stream>>>(ctx, Wot, bo, out);
}